// Round 14
// baseline (252.638 us; speedup 1.0000x reference)
//
#include <hip/hip_runtime.h>

// ConvGeodesic: B=50000, R=5, A=8, K=2, O=32, I=32
// conv[b,n] = sum_k p[b,k] * W[k,n]   (M=50000, K=1280, N=256)
//   p[b,(ra,i)] = sum_t bary[b,ra,t]*signal[b,ra,t,i]
//   W[(ra,i),(c,o)] = sum_kk kernel[r,(c+a)%8,kk,o,i]
// R14: PAGE-GRANULARITY A/B. R5/R6/R8/R13 (four different pipelines) all sit
// at 229-235us with every on-chip pipe <15% and HBM at ~53% — the shared
// invariant is the 384B-per-row-per-iteration signal access (DRAM page closes
// between visits -> ~3 activations/KB). This round: 32-row blocks, K-step
// stages 2 ra-slabs (768B per row visit) via the R13 DMA ring (2 slots,
// 2 stages ahead, FIFO-ordered: W loads issued BEFORE ring refresh).
// Arithmetic = proven 3-term bf16 hi/lo split (absmax 0.125).
// LDS 59392B -> 2 blocks/CU; no reg-cap launch_bounds (R7/R9 spills).
// out[b,:] = relu(conv)[b, argmax_c ||relu(conv)[b,c,:]||, :]

#define B_TOT 50000
#define NRA 40
#define NSTG 20               // stages of 2 slabs
#define SLOT_B 24576          // 32 rows x 768 B
#define P_OFF  49152          // p region: [plane2][slab2][row32][40] halves

typedef __attribute__((ext_vector_type(8))) short short8v;   // 8 bf16 (4 VGPRs)
typedef __attribute__((ext_vector_type(4))) float f32x4;
typedef const __attribute__((address_space(1))) unsigned int* gp1_t;
typedef __attribute__((address_space(3))) unsigned int* lp3_t;

// W planes, n-major k-minor per ra-slab: [ra][n=256][k'=32] bf16 (1.31 MB each)
__device__ __align__(16) unsigned short W_hi_g[NRA * 256 * 32];
__device__ __align__(16) unsigned short W_lo_g[NRA * 256 * 32];

static __device__ __forceinline__ unsigned short f2bf(float x) {   // rne
    unsigned u = __float_as_uint(x);
    u += 0x7FFFu + ((u >> 16) & 1u);
    return (unsigned short)(u >> 16);
}
static __device__ __forceinline__ float bf2f(unsigned short h) {
    return __uint_as_float(((unsigned)h) << 16);
}

__global__ __launch_bounds__(256) void build_w_kernel(const float* __restrict__ kern) {
    int e = blockIdx.x * 256 + threadIdx.x;   // e = ((ra*256)+n)*32 + i
    int i = e & 31;
    int n = (e >> 5) & 255;
    int ra = e >> 13;
    int r = ra >> 3, a = ra & 7;
    int c = n >> 5, o = n & 31;
    int a2 = (c + a) & 7;
    // kernel (R,A,K,O,I); kk stride = 1024
    const float* p = kern + ((((r * 8 + a2) * 2) * 32 + o) * 32 + i);
    float w = p[0] + p[1024];
    unsigned short hi = f2bf(w);
    unsigned short lo = f2bf(w - bf2f(hi));
    W_hi_g[e] = hi;
    W_lo_g[e] = lo;
}

static __device__ __forceinline__ void pcomp(float by0, float by1, float by2,
                                             const float4& a, const float4& b,
                                             const float4& c, float* d) {
    d[0] = fmaf(by2, c.x, fmaf(by1, b.x, by0 * a.x));
    d[1] = fmaf(by2, c.y, fmaf(by1, b.y, by0 * a.y));
    d[2] = fmaf(by2, c.z, fmaf(by1, b.z, by0 * a.z));
    d[3] = fmaf(by2, c.w, fmaf(by1, b.w, by0 * a.w));
}

__global__ __launch_bounds__(256) void conv_geo_kernel(const float* __restrict__ sig,
                                                       const float* __restrict__ bary,
                                                       float* __restrict__ out) {
    __shared__ __align__(16) char lds_raw[59392];

    const int tid  = threadIdx.x;
    const int lane = tid & 63;
    const int wave = tid >> 6;       // 4 waves, wave w owns cols [64w, 64w+64)
    const int b0   = blockIdx.x * 32;

    f32x4 acc[2][4];                 // [mi][ni]
#pragma unroll
    for (int mi = 0; mi < 2; ++mi)
#pragma unroll
        for (int ni = 0; ni < 4; ++ni) acc[mi][ni] = (f32x4){0.f, 0.f, 0.f, 0.f};

    const int wcol = (wave * 64 + (lane & 15)) * 32 + (lane >> 4) * 8;  // W frag base
    const int poff = (lane & 15) * 40 + (lane >> 4) * 8;                // A-frag base (halves)

    // ---- DMA source offsets (pre-inverse-swizzled global cols; m173 pattern) ----
    unsigned soff[6];
#pragma unroll
    for (int j = 0; j < 6; ++j) {
        int L   = j * 4096 + tid * 16;
        int row = L / 768;                      // 0..31
        int col = L - row * 768;
        int scol = col ^ ((row & 7) << 4);      // involution within each 128B block
        int b = b0 + row; if (b > B_TOT - 1) b = B_TOT - 1;
        soff[j] = (unsigned)b * 15360u + (unsigned)scol;
    }
    const char* sigc = (const char*)sig;
    auto issue = [&](int g, int slot) {         // stage g (slabs 2g,2g+1) -> slot
#pragma unroll
        for (int j = 0; j < 6; ++j) {
            const void* gp = sigc + ((size_t)soff[j] + (size_t)g * 768u);
            void* lp = lds_raw + slot * SLOT_B + j * 4096 + tid * 16;
            __builtin_amdgcn_global_load_lds((gp1_t)gp, (lp3_t)lp, 16, 0, 0);
        }
    };

    // prologue: stages 0,1 -> slots 0,1 (12 DMAs in flight)
    issue(0, 0);
    issue(1, 1);

    // pullback thread mapping: row = tid>>3, slab parity = (tid>>2)&1, q = tid&3
    const int pr_row = tid >> 3;
    const int pr_s   = (tid >> 2) & 1;
    const int pr_q   = tid & 3;
    const int pr_swz = (pr_row & 7) << 4;
    int pbv = b0 + pr_row; if (pbv > B_TOT - 1) pbv = B_TOT - 1;
    unsigned short* p_h = (unsigned short*)(lds_raw + P_OFF);

#pragma unroll 1
    for (int g = 0; g < NSTG; ++g) {
        const int slot = g & 1;
        // ---- stage-ready: wait own 6 DMAs (leave next stage's 6 in flight) ----
        if (g < NSTG - 1) asm volatile("s_waitcnt vmcnt(6) lgkmcnt(0)" ::: "memory");
        else              asm volatile("s_waitcnt vmcnt(0) lgkmcnt(0)" ::: "memory");
        __builtin_amdgcn_s_barrier();
        asm volatile("" ::: "memory");

        // ---- consumable loads FIRST (older than the ring refresh) ----
        short8v bh[2][4], bl[2][4];
#pragma unroll
        for (int s = 0; s < 2; ++s) {
            const unsigned short* wh = W_hi_g + (2 * g + s) * 8192 + wcol;
            const unsigned short* wl = W_lo_g + (2 * g + s) * 8192 + wcol;
#pragma unroll
            for (int ni = 0; ni < 4; ++ni) {
                bh[s][ni] = *(const short8v*)(wh + ni * 512);
                bl[s][ni] = *(const short8v*)(wl + ni * 512);
            }
        }
        const float* bp = bary + (size_t)pbv * 120 + (2 * g + pr_s) * 3;
        float by0 = bp[0], by1 = bp[1], by2 = bp[2];

        // ---- cooperative pullback from LDS sig -> p_lds (bf16 hi/lo) ----
        {
            const char* rowp = lds_raw + slot * SLOT_B + pr_row * 768 + pr_s * 384;
            float4 s0 = *(const float4*)(rowp + ((pr_q * 16)      ^ pr_swz));
            float4 s1 = *(const float4*)(rowp + ((pr_q * 16 + 64) ^ pr_swz));
            float4 s2 = *(const float4*)(rowp + 128 + ((pr_q * 16)      ^ pr_swz));
            float4 s3 = *(const float4*)(rowp + 128 + ((pr_q * 16 + 64) ^ pr_swz));
            float4 s4 = *(const float4*)(rowp + 256 + ((pr_q * 16)      ^ pr_swz));
            float4 s5 = *(const float4*)(rowp + 256 + ((pr_q * 16 + 64) ^ pr_swz));
            float pa[4], pb2[4];
            pcomp(by0, by1, by2, s0, s2, s4, pa);    // i = 4q..4q+3
            pcomp(by0, by1, by2, s1, s3, s5, pb2);   // i = 16+4q..16+4q+3
            unsigned short h1[4], l1[4], h2[4], l2[4];
#pragma unroll
            for (int k = 0; k < 4; ++k) {
                h1[k] = f2bf(pa[k]);  l1[k] = f2bf(pa[k]  - bf2f(h1[k]));
                h2[k] = f2bf(pb2[k]); l2[k] = f2bf(pb2[k] - bf2f(h2[k]));
            }
            uint2 H1, H2, L1, L2;
            H1.x = (unsigned)h1[0] | ((unsigned)h1[1] << 16);
            H1.y = (unsigned)h1[2] | ((unsigned)h1[3] << 16);
            H2.x = (unsigned)h2[0] | ((unsigned)h2[1] << 16);
            H2.y = (unsigned)h2[2] | ((unsigned)h2[3] << 16);
            L1.x = (unsigned)l1[0] | ((unsigned)l1[1] << 16);
            L1.y = (unsigned)l1[2] | ((unsigned)l1[3] << 16);
            L2.x = (unsigned)l2[0] | ((unsigned)l2[1] << 16);
            L2.y = (unsigned)l2[2] | ((unsigned)l2[3] << 16);
            int widx = pr_s * 1280 + pr_row * 40 + pr_q * 4;
            *(uint2*)(p_h + widx)             = H1;
            *(uint2*)(p_h + widx + 16)        = H2;
            *(uint2*)(p_h + 2560 + widx)      = L1;
            *(uint2*)(p_h + 2560 + widx + 16) = L2;
        }

        // ---- p ready; sig slot fully consumed (lgkm only; ring in flight) ----
        asm volatile("s_waitcnt lgkmcnt(0)" ::: "memory");
        __builtin_amdgcn_s_barrier();
        asm volatile("" ::: "memory");

        // ---- ring refill LAST (youngest vmem) ----
        if (g + 2 < NSTG) issue(g + 2, slot);

        // ---- MFMA: 2 slabs x 2 mi x 4 ni x 3 terms ----
#pragma unroll
        for (int s = 0; s < 2; ++s)
#pragma unroll
            for (int mi = 0; mi < 2; ++mi) {
                const unsigned short* pr_ = p_h + s * 1280 + mi * 640 + poff;
                short8v ah = *(const short8v*)pr_;
                short8v al = *(const short8v*)(pr_ + 2560);
#pragma unroll
                for (int ni = 0; ni < 4; ++ni) {
                    acc[mi][ni] = __builtin_amdgcn_mfma_f32_16x16x32_bf16(ah, bh[s][ni], acc[mi][ni], 0, 0, 0);
                    acc[mi][ni] = __builtin_amdgcn_mfma_f32_16x16x32_bf16(ah, bl[s][ni], acc[mi][ni], 0, 0, 0);
                    acc[mi][ni] = __builtin_amdgcn_mfma_f32_16x16x32_bf16(al, bh[s][ni], acc[mi][ni], 0, 0, 0);
                }
            }
    }

    // ---- epilogue: relu + norms + argmax + select (single 32-row pass) ----
    // D layout: row = 16*mi + 4*(lane>>4) + j, col = 64*wave + 16*ni + (lane&15)
    float* smem = (float*)lds_raw;   // [32][264]
    const int colb = wave * 64 + (lane & 15);
    const int rsub = (lane >> 4) * 4;
    __syncthreads();
#pragma unroll
    for (int mi = 0; mi < 2; ++mi)
#pragma unroll
        for (int ni = 0; ni < 4; ++ni)
#pragma unroll
            for (int j = 0; j < 4; ++j)
                smem[(mi * 16 + rsub + j) * 264 + colb + ni * 16] =
                    fmaxf(acc[mi][ni][j], 0.0f);
    __syncthreads();
    {
        int bb = tid >> 3;          // 0..31
        int c  = tid & 7;
        float n2 = 0.0f;
#pragma unroll
        for (int t = 0; t < 8; ++t) {
            float4 v = *(const float4*)&smem[bb * 264 + c * 32 + t * 4];
            n2 = fmaf(v.x, v.x, n2); n2 = fmaf(v.y, v.y, n2);
            n2 = fmaf(v.z, v.z, n2); n2 = fmaf(v.w, v.w, n2);
        }
        int bc = c;
#pragma unroll
        for (int m = 1; m < 8; m <<= 1) {   // argmax, tie -> lowest c (numpy first-max)
            float on2 = __shfl_xor(n2, m, 64);
            int obc = __shfl_xor(bc, m, 64);
            if (on2 > n2 || (on2 == n2 && obc < bc)) { n2 = on2; bc = obc; }
        }
        int b = b0 + bb;
        if (b < B_TOT) {
            float4 v = *(const float4*)&smem[bb * 264 + bc * 32 + (tid & 7) * 4];
            *(float4*)&out[(size_t)b * 32 + (tid & 7) * 4] = v;
        }
    }
}

extern "C" void kernel_launch(void* const* d_in, const int* in_sizes, int n_in,
                              void* d_out, int out_size, void* d_ws, size_t ws_size,
                              hipStream_t stream) {
    const float* sig  = (const float*)d_in[0];   // (B,R,A,3,I)
    const float* bary = (const float*)d_in[1];   // (B,R,A,3)
    const float* kern = (const float*)d_in[2];   // (R,A,K,O,I)
    float* out = (float*)d_out;                  // (B,O)

    build_w_kernel<<<(NRA * 256 * 32) / 256, 256, 0, stream>>>(kern);
    conv_geo_kernel<<<(B_TOT + 31) / 32, 256, 0, stream>>>(sig, bary, out);
}